// Round 3
// baseline (588.834 us; speedup 1.0000x reference)
//
#include <hip/hip_runtime.h>
#include <math.h>

// Problem constants (fixed by setup_inputs)
#define BD   1024            // batch B
#define LW   80              // walk length L
#define AA   76              // anchors A = L - w + 1, w = 5
#define NEGS 4               // negatives per anchor
#define D    128             // embed dim
#define PAIRS (BD * AA)      // 77824 (b,a) pairs
#define WAVES_PER_BLOCK 4
#define NBLOCKS (PAIRS / WAVES_PER_BLOCK)   // 19456, exact: 1 pair per wave

// Numerically-stable softplus matching jax.nn.softplus
__device__ __forceinline__ float softplus(float x) {
    return fmaxf(x, 0.0f) + log1pf(__expf(-fabsf(x)));
}

// One (b,a) pair per wave: all 9 row-gathers issued up front (MLP depth 9),
// no inter-pair serialization. 77824 waves total -> ~32 resident waves/CU,
// ~288 rows in flight per CU, far above the ~18 needed to cover ~900cyc
// HBM latency at 6.3 TB/s. launch_bounds(256,8) caps VGPR<=64 for 8 w/SIMD.
__global__ __launch_bounds__(256, 8) void sg_partial(
    const int* __restrict__ walk, const int* __restrict__ neg,
    const float* __restrict__ embed, float* __restrict__ ws)
{
    __shared__ float s_wsum[WAVES_PER_BLOCK];
    const int tid  = threadIdx.x;
    const int lane = tid & 63;
    const int wave = __builtin_amdgcn_readfirstlane(tid >> 6);
    const int p    = blockIdx.x * WAVES_PER_BLOCK + wave;   // < 77824 always
    const int b    = p / AA;
    const int a    = p - b * AA;

    // wave-uniform index loads -> scalar (s_load) broadcasts
    const int* wrow = walk + b * LW + a;
    const int anc = wrow[0];
    const int t0  = wrow[1];
    const int t1  = wrow[2];
    const int t2  = wrow[3];
    const int t3  = wrow[4];
    const int4 nv = *(const int4*)(neg + (size_t)p * NEGS);  // 16B aligned

    // lane i holds float2 slot [2i,2i+1] of each 512B row; all 9 loads batched
    const float* erow = embed + (size_t)(lane * 2);
    const float2 ea = *(const float2*)(erow + (size_t)anc  * D);
    const float2 e0 = *(const float2*)(erow + (size_t)t0   * D);
    const float2 e1 = *(const float2*)(erow + (size_t)t1   * D);
    const float2 e2 = *(const float2*)(erow + (size_t)t2   * D);
    const float2 e3 = *(const float2*)(erow + (size_t)t3   * D);
    const float2 e4 = *(const float2*)(erow + (size_t)nv.x * D);
    const float2 e5 = *(const float2*)(erow + (size_t)nv.y * D);
    const float2 e6 = *(const float2*)(erow + (size_t)nv.z * D);
    const float2 e7 = *(const float2*)(erow + (size_t)nv.w * D);

    float a0v = fmaf(ea.x, e0.x, ea.y * e0.y);
    float a1v = fmaf(ea.x, e1.x, ea.y * e1.y);
    float a2v = fmaf(ea.x, e2.x, ea.y * e2.y);
    float a3v = fmaf(ea.x, e3.x, ea.y * e3.y);
    float a4v = fmaf(ea.x, e4.x, ea.y * e4.y);
    float a5v = fmaf(ea.x, e5.x, ea.y * e5.y);
    float a6v = fmaf(ea.x, e6.x, ea.y * e6.y);
    float a7v = fmaf(ea.x, e7.x, ea.y * e7.y);

    // reduce-scatter butterfly: 10 shuffles; after stage 3 each lane holds one
    // fully-reduced logit (id = lane&7; bit0=1 => negative sample)
    const bool hi1 = lane & 1;
    const bool hi2 = lane & 2;
    const bool hi3 = lane & 4;

    float b0 = (hi1 ? a4v : a0v) + __shfl_xor(hi1 ? a0v : a4v, 1);
    float b1 = (hi1 ? a5v : a1v) + __shfl_xor(hi1 ? a1v : a5v, 1);
    float b2 = (hi1 ? a6v : a2v) + __shfl_xor(hi1 ? a2v : a6v, 1);
    float b3 = (hi1 ? a7v : a3v) + __shfl_xor(hi1 ? a3v : a7v, 1);

    float c0 = (hi2 ? b2 : b0) + __shfl_xor(hi2 ? b0 : b2, 2);
    float c1 = (hi2 ? b3 : b1) + __shfl_xor(hi2 ? b1 : b3, 2);

    float dv = (hi3 ? c1 : c0) + __shfl_xor(hi3 ? c0 : c1, 4);
    dv += __shfl_xor(dv, 8);
    dv += __shfl_xor(dv, 16);
    dv += __shfl_xor(dv, 32);

    // pos logits: softplus(-x); neg logits: softplus(+x)
    float v = softplus(hi1 ? dv : -dv);

    // wave sum (each logit replicated 8x across lanes -> *0.125)
    #pragma unroll
    for (int m = 1; m < 64; m <<= 1) v += __shfl_xor(v, m);

    if (lane == 0) s_wsum[wave] = v * 0.125f;
    __syncthreads();
    if (tid == 0)
        ws[blockIdx.x] = s_wsum[0] + s_wsum[1] + s_wsum[2] + s_wsum[3];
}

__global__ __launch_bounds__(1024) void sg_reduce(
    const float* __restrict__ ws, float* __restrict__ out)
{
    __shared__ float s[16];
    const int tid = threadIdx.x;
    float sum = 0.0f;
    #pragma unroll
    for (int i = 0; i < NBLOCKS / 1024; ++i)   // 19456 = 19 * 1024, exact
        sum += ws[tid + i * 1024];
    #pragma unroll
    for (int m = 1; m < 64; m <<= 1) sum += __shfl_xor(sum, m);
    const int wave = tid >> 6;
    const int lane = tid & 63;
    if (lane == 0) s[wave] = sum;
    __syncthreads();
    if (tid == 0) {
        float acc = 0.0f;
        #pragma unroll
        for (int i = 0; i < 16; ++i) acc += s[i];
        const float total = (float)((size_t)PAIRS * 8);   // 622592 logits
        out[0] = acc * (1.0f / total);
    }
}

extern "C" void kernel_launch(void* const* d_in, const int* in_sizes, int n_in,
                              void* d_out, int out_size, void* d_ws, size_t ws_size,
                              hipStream_t stream) {
    const int*   walk  = (const int*)d_in[0];
    const int*   neg   = (const int*)d_in[1];
    const float* embed = (const float*)d_in[2];
    float* ws  = (float*)d_ws;   // NBLOCKS floats of scratch (~76 KB)
    float* out = (float*)d_out;

    sg_partial<<<NBLOCKS, 256, 0, stream>>>(walk, neg, embed, ws);
    sg_reduce<<<1, 1024, 0, stream>>>(ws, out);
}